// Round 3
// baseline (7608.219 us; speedup 1.0000x reference)
//
#include <hip/hip_runtime.h>

#define HDIM 2048   // LSTM_DIM
#define G4   8192   // 4*HDIM
#define NB   64     // BATCH
#define NT   512    // MAX_STEPS
#define MEL  512
#define KIN  512    // INPUT_SIZE
#define NWG  256

typedef __attribute__((ext_vector_type(8))) short short8;
typedef __attribute__((ext_vector_type(4))) float f32x4;
typedef __attribute__((ext_vector_type(4))) unsigned uint32x4;

__device__ __forceinline__ unsigned short f2bf(float f){
  union { float f; unsigned u; } v; v.f = f;
  return (unsigned short)((v.u + 0x7fffu + ((v.u >> 16) & 1u)) >> 16);
}
__device__ __forceinline__ float sigm(float x){ return 1.f / (1.f + __expf(-x)); }
__device__ __forceinline__ float tanhfast(float x){ return 1.f - 2.f / (__expf(2.f * x) + 1.f); }

// ---------------- fp32 -> bf16 convert ----------------
__global__ void convert_kernel(const float* __restrict__ src, unsigned short* __restrict__ dst, int n4){
  int stride = gridDim.x * blockDim.x;
  for (int i = blockIdx.x * blockDim.x + threadIdx.x; i < n4; i += stride){
    const float4 v = *(const float4*)(src + (size_t)i * 4);
    uint2 pk;
    pk.x = (unsigned)f2bf(v.x) | ((unsigned)f2bf(v.y) << 16);
    pk.y = (unsigned)f2bf(v.z) | ((unsigned)f2bf(v.w) << 16);
    *(uint2*)(dst + (size_t)i * 4) = pk;
  }
}

// ---------------- b_eff = b_ih + b_hh + W_ih @ b_out ; bias0 = b_ih + b_hh ----------------
__global__ void beff_kernel(const float* __restrict__ W_ih, const float* __restrict__ b_ih,
                            const float* __restrict__ b_hh, const float* __restrict__ b_out,
                            float* __restrict__ b_eff, float* __restrict__ bias0){
  int r = blockIdx.x;
  int lane = threadIdx.x;  // 64 threads = 1 wave
  float acc = 0.f;
  for (int k = lane; k < KIN; k += 64) acc += W_ih[(size_t)r * KIN + k] * b_out[k];
  #pragma unroll
  for (int off = 32; off > 0; off >>= 1) acc += __shfl_down(acc, off, 64);
  if (lane == 0){
    float bb = b_ih[r] + b_hh[r];
    bias0[r] = bb;
    b_eff[r] = bb + acc;
  }
}

// ---------------- W_eff = bf16( W_hh + W_ih @ W_out )  [8192 x 2048], K=512 ----------------
__global__ __launch_bounds__(256) void weff_gemm(const float* __restrict__ W_ih, const float* __restrict__ W_out,
                                                 const float* __restrict__ W_hh, unsigned short* __restrict__ Weff){
  __shared__ __align__(16) float As[32][68];  // [k][m]
  __shared__ __align__(16) float Bs[32][68];  // [k][n]
  const int bn = blockIdx.x * 64;
  const int bm = blockIdx.y * 64;
  const int t = threadIdx.x;
  const int tx = t & 15, ty = t >> 4;
  float acc[4][4] = {};
  for (int k0 = 0; k0 < KIN; k0 += 32){
    #pragma unroll
    for (int i = 0; i < 2; i++){
      int f = t + i * 256;
      int row = f >> 3, c4 = (f & 7) * 4;
      const float4 v = *(const float4*)(W_ih + (size_t)(bm + row) * KIN + k0 + c4);
      As[c4 + 0][row] = v.x; As[c4 + 1][row] = v.y; As[c4 + 2][row] = v.z; As[c4 + 3][row] = v.w;
    }
    #pragma unroll
    for (int i = 0; i < 2; i++){
      int f = t + i * 256;
      int kr = f >> 4, c4 = (f & 15) * 4;
      *(float4*)&Bs[kr][c4] = *(const float4*)(W_out + (size_t)(k0 + kr) * HDIM + bn + c4);
    }
    __syncthreads();
    #pragma unroll
    for (int kk = 0; kk < 32; kk++){
      const float4 av = *(const float4*)&As[kk][ty * 4];
      const float4 bv = *(const float4*)&Bs[kk][tx * 4];
      const float ar[4] = {av.x, av.y, av.z, av.w};
      const float br[4] = {bv.x, bv.y, bv.z, bv.w};
      #pragma unroll
      for (int i = 0; i < 4; i++)
        #pragma unroll
        for (int j = 0; j < 4; j++)
          acc[i][j] += ar[i] * br[j];
    }
    __syncthreads();
  }
  #pragma unroll
  for (int i = 0; i < 4; i++){
    const size_t row = (size_t)bm + ty * 4 + i;
    const float4 wh = *(const float4*)(W_hh + row * HDIM + bn + tx * 4);
    uint2 pk;
    pk.x = (unsigned)f2bf(acc[i][0] + wh.x) | ((unsigned)f2bf(acc[i][1] + wh.y) << 16);
    pk.y = (unsigned)f2bf(acc[i][2] + wh.z) | ((unsigned)f2bf(acc[i][3] + wh.w) << 16);
    *(uint2*)(Weff + row * HDIM + bn + tx * 4) = pk;
  }
}

// bypass load (sc0 sc1 -> skip L1+L2, read IC) for barrier slots
__device__ __forceinline__ uint32x4 ld_bypass4(const unsigned* p){
  uint32x4 r;
  asm volatile("global_load_dwordx4 %0, %1, off sc0 sc1\n\t"
               "s_waitcnt vmcnt(0)"
               : "=v"(r) : "v"(p) : "memory");
  return r;
}

// ---------------- lightweight global barrier ----------------
// Arrival: WG leader bypass-stores monotone step count to its own slot (no RMW).
// Wait: wave 0 only; lane L polls slots[4L..4L+4) via one bypass dwordx4, with
// s_sleep backoff (fabric decongestion). Other waves park at s_barrier.
// Acquire: leader agent fence (L2 inv) after detection.
__device__ __forceinline__ void gbar(unsigned* __restrict__ slots, int w, int tid, unsigned tgt){
  __syncthreads();   // all waves' h bypass-stores drained (vmcnt 0) before arrival
  if (tid == 0)
    __hip_atomic_store(slots + w, tgt, __ATOMIC_RELAXED, __HIP_MEMORY_SCOPE_AGENT);
  if (tid < 64){
    const unsigned* sp = slots + tid * 4;
    while (true){
      uint32x4 v = ld_bypass4(sp);
      unsigned m0 = v.x < v.y ? v.x : v.y;
      unsigned m1 = v.z < v.w ? v.z : v.w;
      unsigned m = m0 < m1 ? m0 : m1;
      if (__all((int)(m >= tgt))) break;
      __builtin_amdgcn_s_sleep(1);
    }
  }
  __syncthreads();   // all 256 WGs arrived
  if (tid == 0) __builtin_amdgcn_fence(__ATOMIC_ACQUIRE, "agent");  // inv L1/L2
  __syncthreads();   // inv complete before any h load of next step
}

// ---------------- persistent decoder (split-k, 8 waves) ----------------
// 256 WGs x 512 thr. WG w owns h-columns [8w,8w+8): LDS rows 0..31 = gate rows
// (r = g*8+jl -> global row g*2048+8w+jl), rows 32..33 = W_out rows 2w,2w+1.
// Wave v: batch group g=v&3 (batches 16g..16g+16), k-half kh=v>>2 (k in [1024kh,1024kh+1024)).
// Partial gates summed cross-wave via LDS exchange ex[2][34][68] (pitch 68: write
// pattern 16q-spread, read pattern 8q-spread -> both 2-way/free).
#define LDSW 139264              // 34 rows * 2048 * 2B
#define EXP  68
#define LDSX (LDSW + 2 * 34 * EXP * 4)

__global__ void __launch_bounds__(512, 1) decoder_coop(
    const unsigned short* __restrict__ Whh_b,
    const unsigned short* __restrict__ Weff_b,
    const unsigned short* __restrict__ Wout_b,
    const float* __restrict__ b_eff,
    const float* __restrict__ bias0,
    const float* __restrict__ c0,
    const float* __restrict__ b_out,
    unsigned short* __restrict__ hbuf,   // [2][64][2048] bf16; hbuf[0] pre-filled with bf16(h0)
    unsigned* __restrict__ slots,        // [256] zeroed
    float* __restrict__ out)             // [64][512][512]
{
  extern __shared__ char smem[];
  const int w    = blockIdx.x;
  const int tid  = threadIdx.x;
  const int wave = tid >> 6;
  const int lane = tid & 63;
  const int bcol = lane & 15;          // batch col within tile
  const int q    = lane >> 4;          // k-chunk 0..3 within 32-k slice
  const int g    = wave & 3;           // batch group
  const int kh   = wave >> 2;          // k-half
  const int brow = g * 16 + bcol;      // batch index

  const int r0 = bcol, r1 = 16 + bcol;
  int r2t = 32 + bcol; if (r2t > 33) r2t = 33;   // rows 34..47 are don't-care
  const int r2 = r2t;
  const int s0 = r0 & 7, s1 = r1 & 7, s2 = r2 & 7;

  // ---- initial LDS fill: gate rows from W_hh (step 0), y rows from W_out ----
  {
    const int r = tid >> 4;            // 0..31
    const int u0 = tid & 15;
    const int gx = r >> 3, jl = r & 7;
    const unsigned short* src = Whh_b + ((size_t)(gx * HDIM + w * 8 + jl)) * HDIM;
    char* dstrow = smem + r * 4096;
    const int sw = r & 7;
    #pragma unroll 4
    for (int i = 0; i < 16; i++){
      int u = u0 + i * 16;
      *(int4*)(dstrow + ((u ^ sw) << 4)) = *(const int4*)(src + (size_t)u * 8);
    }
  }
  if (tid < 16){
    const int rr = 32 + (tid & 1);
    const int m  = w * 2 + (tid & 1);
    const unsigned short* src = Wout_b + (size_t)m * HDIM;
    char* dstrow = smem + rr * 4096;
    const int sw = rr & 7;
    for (int i = 0; i < 32; i++){
      int u = (tid >> 1) + i * 8;
      *(int4*)(dstrow + ((u ^ sw) << 4)) = *(const int4*)(src + (size_t)u * 8);
    }
  }
  __syncthreads();

  // ---- per-lane constants ----
  const int jg0 = w * 8 + 2 * q;       // this lane's j pair base (global column index)
  const float be_i0 = b_eff[jg0],            be_i1 = b_eff[jg0 + 1];
  const float be_f0 = b_eff[HDIM + jg0],     be_f1 = b_eff[HDIM + jg0 + 1];
  const float be_g0 = b_eff[2 * HDIM + jg0], be_g1 = b_eff[2 * HDIM + jg0 + 1];
  const float be_o0 = b_eff[3 * HDIM + jg0], be_o1 = b_eff[3 * HDIM + jg0 + 1];
  const float byo0 = b_out[2 * w], byo1 = b_out[2 * w + 1];
  float cst0 = 0.f, cst1 = 0.f;        // c-state for the 2 owned (j,b) pairs (waves 0..3)
  float* ex = (float*)(smem + LDSW);
  const int ecol = g * 16 + bcol;

  for (int t = 0; t < NT; t++){
    if (t == 1){
      // swap gate rows to W_eff (after step-0 barrier)
      const int r = tid >> 4;
      const int u0 = tid & 15;
      const int gx = r >> 3, jl = r & 7;
      const unsigned short* src = Weff_b + ((size_t)(gx * HDIM + w * 8 + jl)) * HDIM;
      char* dstrow = smem + r * 4096;
      const int sw = r & 7;
      #pragma unroll 4
      for (int i = 0; i < 16; i++){
        int u = u0 + i * 16;
        *(int4*)(dstrow + ((u ^ sw) << 4)) = *(const int4*)(src + (size_t)u * 8);
      }
      __syncthreads();
    }
    const unsigned short* hsrc = hbuf + (size_t)(t & 1) * NB * HDIM;
    const unsigned short* hs = hsrc + (size_t)brow * HDIM + kh * 1024 + q * 8;

    f32x4 acc0 = {0.f,0.f,0.f,0.f}, acc1 = {0.f,0.f,0.f,0.f}, acc2 = {0.f,0.f,0.f,0.f};
    #pragma unroll 4
    for (int kk = 0; kk < 32; kk++){
      const short8 bv = *(const short8*)(hs + kk * 32);
      const int un = (kh * 32 + kk) * 4 + q;
      const short8 a0 = *(const short8*)(smem + r0 * 4096 + ((un ^ s0) << 4));
      const short8 a1 = *(const short8*)(smem + r1 * 4096 + ((un ^ s1) << 4));
      const short8 a2 = *(const short8*)(smem + r2 * 4096 + ((un ^ s2) << 4));
      acc0 = __builtin_amdgcn_mfma_f32_16x16x32_bf16(a0, bv, acc0, 0, 0, 0);
      acc1 = __builtin_amdgcn_mfma_f32_16x16x32_bf16(a1, bv, acc1, 0, 0, 0);
      acc2 = __builtin_amdgcn_mfma_f32_16x16x32_bf16(a2, bv, acc2, 0, 0, 0);
    }

    // ---- cross-wave partial-gate exchange ----
    #pragma unroll
    for (int e = 0; e < 4; e++){
      ex[(kh * 34 + (q * 4 + e)) * EXP + ecol]      = acc0[e];   // rows 0..15: i,f
      ex[(kh * 34 + 16 + (q * 4 + e)) * EXP + ecol] = acc1[e];   // rows 16..31: g,o
    }
    if (q == 0){
      ex[(kh * 34 + 32) * EXP + ecol] = acc2[0];                 // y rows
      ex[(kh * 34 + 33) * EXP + ecol] = acc2[1];
    }
    __syncthreads();

    if (wave < 4){
      const int jl0 = 2 * q;
      #define EXR(row) (ex[(row) * EXP + ecol] + ex[(34 + (row)) * EXP + ecol])
      const float ai0 = EXR(jl0 + 0),  ai1 = EXR(jl0 + 1);
      const float af0 = EXR(jl0 + 8),  af1 = EXR(jl0 + 9);
      const float ag0 = EXR(jl0 + 16), ag1 = EXR(jl0 + 17);
      const float ao0 = EXR(jl0 + 24), ao1 = EXR(jl0 + 25);

      float bi0, bi1, bf0, bf1, bg0, bg1, bo0, bo1;
      if (t == 0){
        bi0 = bias0[jg0];            bi1 = bias0[jg0 + 1];
        bf0 = bias0[HDIM + jg0];     bf1 = bias0[HDIM + jg0 + 1];
        bg0 = bias0[2 * HDIM + jg0]; bg1 = bias0[2 * HDIM + jg0 + 1];
        bo0 = bias0[3 * HDIM + jg0]; bo1 = bias0[3 * HDIM + jg0 + 1];
        cst0 = c0[(size_t)brow * HDIM + jg0];
        cst1 = c0[(size_t)brow * HDIM + jg0 + 1];
      } else {
        bi0 = be_i0; bi1 = be_i1; bf0 = be_f0; bf1 = be_f1;
        bg0 = be_g0; bg1 = be_g1; bo0 = be_o0; bo1 = be_o1;
      }

      const float gi0 = sigm(ai0 + bi0), gf0 = sigm(af0 + bf0);
      const float gg0 = tanhfast(ag0 + bg0), go0 = sigm(ao0 + bo0);
      const float cn0 = gf0 * cst0 + gi0 * gg0;
      const float hn0 = go0 * tanhfast(cn0);
      const float gi1 = sigm(ai1 + bi1), gf1 = sigm(af1 + bf1);
      const float gg1 = tanhfast(ag1 + bg1), go1 = sigm(ao1 + bo1);
      const float cn1 = gf1 * cst1 + gi1 * gg1;
      const float hn1 = go1 * tanhfast(cn1);
      cst0 = cn0; cst1 = cn1;

      // h store: agent-scope bypass store -> lands at IC, no wbl2 fence needed
      unsigned short* hdst = hbuf + (size_t)((t + 1) & 1) * NB * HDIM;
      const unsigned hpk = (unsigned)f2bf(hn0) | ((unsigned)f2bf(hn1) << 16);
      __hip_atomic_store((unsigned*)(hdst + (size_t)brow * HDIM + jg0), hpk,
                         __ATOMIC_RELAXED, __HIP_MEMORY_SCOPE_AGENT);

      if (t >= 1 && q == 0){
        float2 yv; yv.x = EXR(32) + byo0; yv.y = EXR(33) + byo1;
        *(float2*)(out + ((size_t)brow * NT + (t - 1)) * MEL + 2 * w) = yv;
      }
    }
    gbar(slots, w, tid, (unsigned)(t + 1));
  }

  // ---- final output frame: y_511 = h_512 @ W_out^T + b_out, h_512 in hbuf[0] ----
  {
    const unsigned short* hs = hbuf + (size_t)brow * HDIM + kh * 1024 + q * 8;
    f32x4 acc = {0.f,0.f,0.f,0.f};
    #pragma unroll 4
    for (int kk = 0; kk < 32; kk++){
      const short8 bv = *(const short8*)(hs + kk * 32);
      const int un = (kh * 32 + kk) * 4 + q;
      const short8 a2 = *(const short8*)(smem + r2 * 4096 + ((un ^ s2) << 4));
      acc = __builtin_amdgcn_mfma_f32_16x16x32_bf16(a2, bv, acc, 0, 0, 0);
    }
    if (q == 0){
      ex[(kh * 34 + 32) * EXP + ecol] = acc[0];
      ex[(kh * 34 + 33) * EXP + ecol] = acc[1];
    }
    __syncthreads();
    if (wave < 4 && q == 0){
      float2 yv; yv.x = EXR(32) + byo0; yv.y = EXR(33) + byo1;
      *(float2*)(out + ((size_t)brow * NT + 511) * MEL + 2 * w) = yv;
    }
  }
}

extern "C" void kernel_launch(void* const* d_in, const int* in_sizes, int n_in,
                              void* d_out, int out_size, void* d_ws, size_t ws_size,
                              hipStream_t stream){
  (void)in_sizes; (void)n_in; (void)out_size; (void)ws_size;
  const float* h0    = (const float*)d_in[1];
  const float* c0    = (const float*)d_in[2];
  const float* W_ih  = (const float*)d_in[3];
  const float* W_hh  = (const float*)d_in[4];
  const float* b_ih  = (const float*)d_in[5];
  const float* b_hh  = (const float*)d_in[6];
  const float* W_out = (const float*)d_in[7];
  const float* b_out = (const float*)d_in[8];
  float* out = (float*)d_out;

  char* p = (char*)d_ws;
  unsigned short* weff_b = (unsigned short*)p; p += (size_t)G4 * HDIM * 2;   // 33.5 MB
  unsigned short* whh_b  = (unsigned short*)p; p += (size_t)G4 * HDIM * 2;   // 33.5 MB
  unsigned short* wout_b = (unsigned short*)p; p += (size_t)MEL * HDIM * 2;  // 2 MB
  float* beff  = (float*)p; p += (size_t)G4 * 4;
  float* bias0 = (float*)p; p += (size_t)G4 * 4;
  unsigned short* hbuf = (unsigned short*)p; p += (size_t)2 * NB * HDIM * 2; // 512 KB
  unsigned* slots = (unsigned*)p; p += NWG * sizeof(unsigned);

  hipMemsetAsync(slots, 0, NWG * sizeof(unsigned), stream);
  convert_kernel<<<2048, 256, 0, stream>>>(W_hh, whh_b, G4 * HDIM / 4);
  convert_kernel<<<256, 256, 0, stream>>>(W_out, wout_b, MEL * HDIM / 4);
  convert_kernel<<<64, 256, 0, stream>>>(h0, hbuf, NB * HDIM / 4);
  beff_kernel<<<G4, 64, 0, stream>>>(W_ih, b_ih, b_hh, b_out, beff, bias0);
  weff_gemm<<<dim3(HDIM / 64, G4 / 64), 256, 0, stream>>>(W_ih, W_out, W_hh, weff_b);

  hipFuncSetAttribute((const void*)decoder_coop, hipFuncAttributeMaxDynamicSharedMemorySize, LDSX);
  void* kargs[] = { (void*)&whh_b, (void*)&weff_b, (void*)&wout_b, (void*)&beff, (void*)&bias0,
                    (void*)&c0, (void*)&b_out, (void*)&hbuf, (void*)&slots, (void*)&out };
  hipLaunchCooperativeKernel((const void*)decoder_coop, dim3(256), dim3(512), kargs, LDSX, stream);
}

// Round 4
// 6647.549 us; speedup vs baseline: 1.1445x; 1.1445x over previous
//
#include <hip/hip_runtime.h>

#define HDIM 2048   // LSTM_DIM
#define G4   8192   // 4*HDIM
#define NB   64     // BATCH
#define NT   512    // MAX_STEPS
#define MEL  512
#define KIN  512    // INPUT_SIZE
#define NWG  256

typedef __attribute__((ext_vector_type(8))) short short8;
typedef __attribute__((ext_vector_type(4))) float f32x4;
typedef __attribute__((ext_vector_type(4))) unsigned uint32x4;

__device__ __forceinline__ unsigned short f2bf(float f){
  union { float f; unsigned u; } v; v.f = f;
  return (unsigned short)((v.u + 0x7fffu + ((v.u >> 16) & 1u)) >> 16);
}
__device__ __forceinline__ float sigm(float x){ return 1.f / (1.f + __expf(-x)); }
__device__ __forceinline__ float tanhfast(float x){ return 1.f - 2.f / (__expf(2.f * x) + 1.f); }

__device__ __forceinline__ f32x4 MF(short8 a, short8 b, f32x4 c){
  return __builtin_amdgcn_mfma_f32_16x16x32_bf16(a, b, c, 0, 0, 0);
}
__device__ __forceinline__ short8 as8(uint32x4 u){
  union { uint32x4 u; short8 s; } x; x.u = u; return x.s;
}
// IC bypass 16B load (no waitcnt inside; caller waits via counted vmcnt)
__device__ __forceinline__ void ld4b(uint32x4& d, const unsigned short* p){
  asm volatile("global_load_dwordx4 %0, %1, off sc0 sc1"
               : "=&v"(d) : "v"(p) : "memory");
}
// bypass load with wait (barrier slot poll)
__device__ __forceinline__ uint32x4 ld_bypass4(const unsigned* p){
  uint32x4 r;
  asm volatile("global_load_dwordx4 %0, %1, off sc0 sc1\n\t"
               "s_waitcnt vmcnt(0)"
               : "=v"(r) : "v"(p) : "memory");
  return r;
}

// ---------------- fp32 -> bf16 convert ----------------
__global__ void convert_kernel(const float* __restrict__ src, unsigned short* __restrict__ dst, int n4){
  int stride = gridDim.x * blockDim.x;
  for (int i = blockIdx.x * blockDim.x + threadIdx.x; i < n4; i += stride){
    const float4 v = *(const float4*)(src + (size_t)i * 4);
    uint2 pk;
    pk.x = (unsigned)f2bf(v.x) | ((unsigned)f2bf(v.y) << 16);
    pk.y = (unsigned)f2bf(v.z) | ((unsigned)f2bf(v.w) << 16);
    *(uint2*)(dst + (size_t)i * 4) = pk;
  }
}

// ---------------- b_eff = b_ih + b_hh + W_ih @ b_out ----------------
__global__ void beff_kernel(const float* __restrict__ W_ih, const float* __restrict__ b_ih,
                            const float* __restrict__ b_hh, const float* __restrict__ b_out,
                            float* __restrict__ b_eff){
  int r = blockIdx.x;
  int lane = threadIdx.x;  // 64 threads = 1 wave
  float acc = 0.f;
  for (int k = lane; k < KIN; k += 64) acc += W_ih[(size_t)r * KIN + k] * b_out[k];
  #pragma unroll
  for (int off = 32; off > 0; off >>= 1) acc += __shfl_down(acc, off, 64);
  if (lane == 0) b_eff[r] = b_ih[r] + b_hh[r] + acc;
}

// ---------------- ym1[b][m] = Wout[m]·h0[b] + b_out[m] ----------------
__global__ void ym1_kernel(const float* __restrict__ Wout, const float* __restrict__ h0,
                           const float* __restrict__ b_out, float* __restrict__ ym1){
  const int b = blockIdx.x;
  const int m = blockIdx.y * 64 + threadIdx.x;
  const float* wr = Wout + (size_t)m * HDIM;
  const float* hr = h0 + (size_t)b * HDIM;
  float a0 = 0.f, a1 = 0.f, a2 = 0.f, a3 = 0.f;
  for (int k = 0; k < HDIM; k += 4){
    const float4 wv = *(const float4*)(wr + k);
    const float4 hv = *(const float4*)(hr + k);
    a0 += wv.x * hv.x; a1 += wv.y * hv.y; a2 += wv.z * hv.z; a3 += wv.w * hv.w;
  }
  ym1[(size_t)b * MEL + m] = a0 + a1 + a2 + a3 + b_out[m];
}

// ---------------- corr[r][b] = W_ih[r]·ym1[b] ----------------
__global__ void corr_kernel(const float* __restrict__ Wih, const float* __restrict__ ym1,
                            float* __restrict__ corr){
  const int r = blockIdx.x;
  const int b = threadIdx.x;
  const float* wr = Wih + (size_t)r * KIN;
  const float* yr = ym1 + (size_t)b * MEL;
  float a0 = 0.f, a1 = 0.f, a2 = 0.f, a3 = 0.f;
  for (int m = 0; m < KIN; m += 4){
    const float4 wv = *(const float4*)(wr + m);
    const float4 yv = *(const float4*)(yr + m);
    a0 += wv.x * yv.x; a1 += wv.y * yv.y; a2 += wv.z * yv.z; a3 += wv.w * yv.w;
  }
  corr[(size_t)r * NB + b] = a0 + a1 + a2 + a3;
}

// ---------------- W_eff = bf16( W_hh + W_ih @ W_out )  [8192 x 2048], K=512 ----------------
__global__ __launch_bounds__(256) void weff_gemm(const float* __restrict__ W_ih, const float* __restrict__ W_out,
                                                 const float* __restrict__ W_hh, unsigned short* __restrict__ Weff){
  __shared__ __align__(16) float As[32][68];  // [k][m]
  __shared__ __align__(16) float Bs[32][68];  // [k][n]
  const int bn = blockIdx.x * 64;
  const int bm = blockIdx.y * 64;
  const int t = threadIdx.x;
  const int tx = t & 15, ty = t >> 4;
  float acc[4][4] = {};
  for (int k0 = 0; k0 < KIN; k0 += 32){
    #pragma unroll
    for (int i = 0; i < 2; i++){
      int f = t + i * 256;
      int row = f >> 3, c4 = (f & 7) * 4;
      const float4 v = *(const float4*)(W_ih + (size_t)(bm + row) * KIN + k0 + c4);
      As[c4 + 0][row] = v.x; As[c4 + 1][row] = v.y; As[c4 + 2][row] = v.z; As[c4 + 3][row] = v.w;
    }
    #pragma unroll
    for (int i = 0; i < 2; i++){
      int f = t + i * 256;
      int kr = f >> 4, c4 = (f & 15) * 4;
      *(float4*)&Bs[kr][c4] = *(const float4*)(W_out + (size_t)(k0 + kr) * HDIM + bn + c4);
    }
    __syncthreads();
    #pragma unroll
    for (int kk = 0; kk < 32; kk++){
      const float4 av = *(const float4*)&As[kk][ty * 4];
      const float4 bv = *(const float4*)&Bs[kk][tx * 4];
      const float ar[4] = {av.x, av.y, av.z, av.w};
      const float br[4] = {bv.x, bv.y, bv.z, bv.w};
      #pragma unroll
      for (int i = 0; i < 4; i++)
        #pragma unroll
        for (int j = 0; j < 4; j++)
          acc[i][j] += ar[i] * br[j];
    }
    __syncthreads();
  }
  #pragma unroll
  for (int i = 0; i < 4; i++){
    const size_t row = (size_t)bm + ty * 4 + i;
    const float4 wh = *(const float4*)(W_hh + row * HDIM + bn + tx * 4);
    uint2 pk;
    pk.x = (unsigned)f2bf(acc[i][0] + wh.x) | ((unsigned)f2bf(acc[i][1] + wh.y) << 16);
    pk.y = (unsigned)f2bf(acc[i][2] + wh.z) | ((unsigned)f2bf(acc[i][3] + wh.w) << 16);
    *(uint2*)(Weff + row * HDIM + bn + tx * 4) = pk;
  }
}

// ---------------- lightweight global barrier (NO fence: all cross-WG data is IC-coherent) ----
__device__ __forceinline__ void gbar(unsigned* __restrict__ slots, int w, int tid, unsigned tgt){
  __syncthreads();   // all waves' h stores drained (vmcnt 0) before arrival
  if (tid == 0)
    __hip_atomic_store(slots + w, tgt, __ATOMIC_RELAXED, __HIP_MEMORY_SCOPE_AGENT);
  if (tid < 64){
    const unsigned* sp = slots + tid * 4;
    while (true){
      uint32x4 vv = ld_bypass4(sp);
      unsigned m0 = vv.x < vv.y ? vv.x : vv.y;
      unsigned m1 = vv.z < vv.w ? vv.z : vv.w;
      unsigned m = m0 < m1 ? m0 : m1;
      if (__all((int)(m >= tgt))) break;
      __builtin_amdgcn_s_sleep(1);
    }
  }
  __syncthreads();
}

// ---------------- persistent decoder: weights in VGPRs ----------------
// 256 WGs x 512 thr (8 waves). WG w owns h-cols [8w,8w+8) -> 32 gate rows + 2 W_out rows.
// Wave v holds A-fragments for k-slice [256v,256v+256) in VGPRs (A0: rows 0-15 = i|f,
// A1: rows 16-31 = g|o, Ay: W_out rows 2w,2w+1 + 14 zero rows).
// Per step: 8 k32-iters, 4 batch-tiles; B (h) via IC-bypass loads, double-buffered regs.
// Gate partials summed via LDS exchange exf[8v][32row][64b] (phys_b = b ^ ((row&7)<<2)).
#define EXYOFF 16384               // f32 index of y-exchange
#define LDSX   (16384*4 + 8*2*64*4)  // 64KB gates + 4KB y = 69632

__global__ void __launch_bounds__(512, 2) decoder_coop(
    const unsigned short* __restrict__ Weff_b,
    const unsigned short* __restrict__ Wout_b,
    const float* __restrict__ b_eff,
    const float* __restrict__ corr,
    const float* __restrict__ c0,
    const float* __restrict__ b_out,
    unsigned short* __restrict__ hbuf,   // [2][64][2048] bf16; hbuf[0] = bf16(h0)
    unsigned* __restrict__ slots,        // [256] zeroed
    float* __restrict__ out)             // [64][512][512]
{
  extern __shared__ char smem[];
  float* exf = (float*)smem;
  float* eyf = exf + EXYOFF;
  const int w    = blockIdx.x;
  const int tid  = threadIdx.x;
  const int v    = tid >> 6;           // wave = k-slice owner
  const int lane = tid & 63;
  const int col  = lane & 15;
  const int q    = lane >> 4;
  const int kbase = v * 256;

  // ---- A-fragment preload into VGPRs ----
  short8 A0[8], A1[8], Ay[8];
  #pragma unroll
  for (int it = 0; it < 8; ++it){
    {
      const int row = col;
      const int grow = (row >> 3) * HDIM + w * 8 + (row & 7);
      A0[it] = *(const short8*)(Weff_b + (size_t)grow * HDIM + kbase + it * 32 + q * 8);
    }
    {
      const int row = 16 + col;
      const int grow = (row >> 3) * HDIM + w * 8 + (row & 7);
      A1[it] = *(const short8*)(Weff_b + (size_t)grow * HDIM + kbase + it * 32 + q * 8);
    }
    if (col < 2)
      Ay[it] = *(const short8*)(Wout_b + (size_t)(w * 2 + col) * HDIM + kbase + it * 32 + q * 8);
    else { short8 z = {0,0,0,0,0,0,0,0}; Ay[it] = z; }
  }

  // ---- reduction-thread constants (tid<256: thread = (j, batch-pair b2)) ----
  const int j  = tid & 7;
  const int b2 = (tid >> 3) & 31;
  const int rj = w * 8 + j;
  float be[4], cE[4], cO[4];
  float cs_e = 0.f, cs_o = 0.f;
  if (tid < 256){
    #pragma unroll
    for (int g = 0; g < 4; ++g){
      be[g] = b_eff[g * HDIM + rj];
      const float2 cc = *(const float2*)(corr + ((size_t)(g * HDIM + rj)) * NB + 2 * b2);
      cE[g] = cc.x; cO[g] = cc.y;
    }
    cs_e = c0[(size_t)(2 * b2) * HDIM + rj];
    cs_o = c0[(size_t)(2 * b2 + 1) * HDIM + rj];
  }
  float byo = 0.f; int yp = 0, yb = 0;
  if (tid >= 256 && tid < 384){
    const int yt = tid - 256; yp = yt & 1; yb = yt >> 1; byo = b_out[w * 2 + yp];
  }

  // per-lane B element-offset bases (const over t)
  int boff[4];
  #pragma unroll
  for (int bt = 0; bt < 4; ++bt) boff[bt] = (bt * 16 + col) * HDIM + kbase + q * 8;

  for (int t = 0; t < NT; ++t){
    const unsigned short* hcur = hbuf + (size_t)(t & 1) * NB * HDIM;
    uint32x4 G0[4], G1[4];
    f32x4 acc0[4], acc1[4], accy[4];
    #pragma unroll
    for (int bt = 0; bt < 4; ++bt){ f32x4 z = {0.f,0.f,0.f,0.f}; acc0[bt]=z; acc1[bt]=z; accy[bt]=z; }

    #pragma unroll
    for (int bt = 0; bt < 4; ++bt) ld4b(G0[bt], hcur + boff[bt]);       // group 0
    #pragma unroll
    for (int it = 0; it < 8; ++it){
      if (it < 7){
        if ((it & 1) == 0){
          #pragma unroll
          for (int bt = 0; bt < 4; ++bt) ld4b(G1[bt], hcur + boff[bt] + (it + 1) * 32);
        } else {
          #pragma unroll
          for (int bt = 0; bt < 4; ++bt) ld4b(G0[bt], hcur + boff[bt] + (it + 1) * 32);
        }
        asm volatile("s_waitcnt vmcnt(4)" ::: "memory");
      } else {
        asm volatile("s_waitcnt vmcnt(0)" ::: "memory");
      }
      __builtin_amdgcn_sched_barrier(0);
      if ((it & 1) == 0){
        #pragma unroll
        for (int bt = 0; bt < 4; ++bt){
          const short8 bv = as8(G0[bt]);
          acc0[bt] = MF(A0[it], bv, acc0[bt]);
          acc1[bt] = MF(A1[it], bv, acc1[bt]);
          accy[bt] = MF(Ay[it], bv, accy[bt]);
        }
      } else {
        #pragma unroll
        for (int bt = 0; bt < 4; ++bt){
          const short8 bv = as8(G1[bt]);
          acc0[bt] = MF(A0[it], bv, acc0[bt]);
          acc1[bt] = MF(A1[it], bv, acc1[bt]);
          accy[bt] = MF(Ay[it], bv, accy[bt]);
        }
      }
    }

    // ---- exchange stores (swizzled: phys_b = b ^ ((row&7)<<2), <=2-way) ----
    #pragma unroll
    for (int bt = 0; bt < 4; ++bt){
      const int b = bt * 16 + col;
      #pragma unroll
      for (int e = 0; e < 4; ++e){
        const int r0 = q * 4 + e;
        exf[(v * 32 + r0) * 64 + (b ^ ((r0 & 7) << 2))] = acc0[bt][e];
        const int r1 = 16 + q * 4 + e;
        exf[(v * 32 + r1) * 64 + (b ^ ((r1 & 7) << 2))] = acc1[bt][e];
      }
      if (q == 0){
        eyf[(v * 2 + 0) * 64 + b] = accy[bt][0];
        eyf[(v * 2 + 1) * 64 + b] = accy[bt][1];
      }
    }
    __syncthreads();

    if (tid < 256){
      // ---- 8-way k-partial reduction + LSTM cell for (j, 2*b2) and (j, 2*b2+1) ----
      float ge[4] = {0,0,0,0}, go[4] = {0,0,0,0};
      #pragma unroll
      for (int g = 0; g < 4; ++g){
        #pragma unroll
        for (int vv = 0; vv < 8; ++vv){
          const float2 pr = *(const float2*)&exf[(vv * 32 + g * 8 + j) * 64 + ((2 * b2) ^ (j << 2))];
          ge[g] += pr.x; go[g] += pr.y;
        }
      }
      float ie = ge[0] + be[0], fe = ge[1] + be[1], gge = ge[2] + be[2], oe = ge[3] + be[3];
      float io = go[0] + be[0], fo = go[1] + be[1], ggo = go[2] + be[2], oo = go[3] + be[3];
      if (t == 0){
        ie -= cE[0]; fe -= cE[1]; gge -= cE[2]; oe -= cE[3];
        io -= cO[0]; fo -= cO[1]; ggo -= cO[2]; oo -= cO[3];
      }
      const float gi0 = sigm(ie), gf0 = sigm(fe), gg0 = tanhfast(gge), go0 = sigm(oe);
      cs_e = gf0 * cs_e + gi0 * gg0;
      const float hn_e = go0 * tanhfast(cs_e);
      const float gi1 = sigm(io), gf1 = sigm(fo), gg1 = tanhfast(ggo), go1 = sigm(oo);
      cs_o = gf1 * cs_o + gi1 * gg1;
      const float hn_o = go1 * tanhfast(cs_o);

      // pack 2 adjacent j via shfl, store 4B to IC (agent scope)
      const float pe = __shfl_xor(hn_e, 1, 64);
      const float po = __shfl_xor(hn_o, 1, 64);
      unsigned short* hdst = hbuf + (size_t)((t + 1) & 1) * NB * HDIM;
      if ((j & 1) == 0){
        const unsigned pk = (unsigned)f2bf(hn_e) | ((unsigned)f2bf(pe) << 16);
        __hip_atomic_store((unsigned*)(hdst + (size_t)(2 * b2) * HDIM + rj), pk,
                           __ATOMIC_RELAXED, __HIP_MEMORY_SCOPE_AGENT);
      } else {
        const unsigned pk = (unsigned)f2bf(po) | ((unsigned)f2bf(hn_o) << 16);
        __hip_atomic_store((unsigned*)(hdst + (size_t)(2 * b2 + 1) * HDIM + rj - 1), pk,
                           __ATOMIC_RELAXED, __HIP_MEMORY_SCOPE_AGENT);
      }
    } else if (tid < 384 && t >= 1){
      // ---- y reduction: out[b][t-1][2w+yp] ----
      float yv = byo;
      #pragma unroll
      for (int vv = 0; vv < 8; ++vv) yv += eyf[(vv * 2 + yp) * 64 + yb];
      out[((size_t)yb * NT + (t - 1)) * MEL + w * 2 + yp] = yv;
    }
    gbar(slots, w, tid, (unsigned)(t + 1));
  }

  // ---- final frame: y_511 from h_512 (in hbuf[0], NT even) ----
  {
    const unsigned short* hcur = hbuf;   // (NT&1)==0
    f32x4 accy[4];
    #pragma unroll
    for (int bt = 0; bt < 4; ++bt){ f32x4 z = {0.f,0.f,0.f,0.f}; accy[bt] = z; }
    #pragma unroll
    for (int it = 0; it < 8; ++it){
      uint32x4 g[4];
      #pragma unroll
      for (int bt = 0; bt < 4; ++bt) ld4b(g[bt], hcur + boff[bt] + it * 32);
      asm volatile("s_waitcnt vmcnt(0)" ::: "memory");
      __builtin_amdgcn_sched_barrier(0);
      #pragma unroll
      for (int bt = 0; bt < 4; ++bt) accy[bt] = MF(Ay[it], as8(g[bt]), accy[bt]);
    }
    #pragma unroll
    for (int bt = 0; bt < 4; ++bt){
      const int b = bt * 16 + col;
      if (q == 0){
        eyf[(v * 2 + 0) * 64 + b] = accy[bt][0];
        eyf[(v * 2 + 1) * 64 + b] = accy[bt][1];
      }
    }
    __syncthreads();
    if (tid >= 256 && tid < 384){
      float yv = byo;
      #pragma unroll
      for (int vv = 0; vv < 8; ++vv) yv += eyf[(vv * 2 + yp) * 64 + yb];
      out[((size_t)yb * NT + 511) * MEL + w * 2 + yp] = yv;
    }
  }
}

extern "C" void kernel_launch(void* const* d_in, const int* in_sizes, int n_in,
                              void* d_out, int out_size, void* d_ws, size_t ws_size,
                              hipStream_t stream){
  (void)in_sizes; (void)n_in; (void)out_size; (void)ws_size;
  const float* h0    = (const float*)d_in[1];
  const float* c0    = (const float*)d_in[2];
  const float* W_ih  = (const float*)d_in[3];
  const float* W_hh  = (const float*)d_in[4];
  const float* b_ih  = (const float*)d_in[5];
  const float* b_hh  = (const float*)d_in[6];
  const float* W_out = (const float*)d_in[7];
  const float* b_out = (const float*)d_in[8];
  float* out = (float*)d_out;

  char* p = (char*)d_ws;
  unsigned short* weff_b = (unsigned short*)p; p += (size_t)G4 * HDIM * 2;   // 33.5 MB
  unsigned short* wout_b = (unsigned short*)p; p += (size_t)MEL * HDIM * 2;  // 2 MB
  float* beff = (float*)p;  p += (size_t)G4 * 4;
  float* corr = (float*)p;  p += (size_t)G4 * NB * 4;                        // 2 MB
  float* ym1  = (float*)p;  p += (size_t)NB * MEL * 4;                       // 128 KB
  unsigned short* hbuf = (unsigned short*)p; p += (size_t)2 * NB * HDIM * 2; // 512 KB
  unsigned* slots = (unsigned*)p; p += NWG * sizeof(unsigned);

  hipMemsetAsync(slots, 0, NWG * sizeof(unsigned), stream);
  convert_kernel<<<256, 256, 0, stream>>>(W_out, wout_b, MEL * HDIM / 4);
  convert_kernel<<<64, 256, 0, stream>>>(h0, hbuf, NB * HDIM / 4);
  beff_kernel<<<G4, 64, 0, stream>>>(W_ih, b_ih, b_hh, b_out, beff);
  ym1_kernel<<<dim3(NB, MEL / 64), 64, 0, stream>>>(W_out, h0, b_out, ym1);
  corr_kernel<<<G4, NB, 0, stream>>>(W_ih, ym1, corr);
  weff_gemm<<<dim3(HDIM / 64, G4 / 64), 256, 0, stream>>>(W_ih, W_out, W_hh, weff_b);

  hipFuncSetAttribute((const void*)decoder_coop, hipFuncAttributeMaxDynamicSharedMemorySize, LDSX);
  void* kargs[] = { (void*)&weff_b, (void*)&wout_b, (void*)&beff, (void*)&corr,
                    (void*)&c0, (void*)&b_out, (void*)&hbuf, (void*)&slots, (void*)&out };
  hipLaunchCooperativeKernel((const void*)decoder_coop, dim3(NWG), dim3(512), kargs, LDSX, stream);
}